// Round 14
// baseline (188.432 us; speedup 1.0000x reference)
//
#include <hip/hip_runtime.h>

// ---------------------------------------------------------------------------
// Attention block: out = (softmax((q Wq^T+bq)(k Wk^T+bk)^T / 8) (v Wv^T+bv)) Wo^T + bo
// B=4 T=2048 C=1024 H=16 CH=64.  Internal compute bf16 MFMA + f32 accum.
// R13: fp32->bf16 conversion moved OUT of the projection GEMMs into one
//      streaming cvt_all kernel; proj = 3 all-bf16 GEMMs sharing gemm_out's
//      glds-both-sides pipelined body.  Attn reverted to R9/R10 form.
// ---------------------------------------------------------------------------

typedef short bf8 __attribute__((ext_vector_type(8)));      // 8 bf16 (4 VGPRs)
typedef float f4 __attribute__((ext_vector_type(4)));
typedef float f16v __attribute__((ext_vector_type(16)));
typedef unsigned short u16;

#define AS1 __attribute__((address_space(1)))
#define AS3 __attribute__((address_space(3)))

__device__ __forceinline__ u16 f2b(float f) {
  unsigned u = __builtin_bit_cast(unsigned, f);
  u += 0x7FFFu + ((u >> 16) & 1u);          // RNE
  return (u16)(u >> 16);
}

__device__ __forceinline__ unsigned cvtpk(float lo, float hi) {
  unsigned r;
  asm("v_cvt_pk_bf16_f32 %0, %1, %2" : "=v"(r) : "v"(lo), "v"(hi));
  return r;
}

__device__ __forceinline__ void swap32(unsigned& a, unsigned& b) {
  asm("v_permlane32_swap_b32 %0, %1" : "+v"(a), "+v"(b));
}

// ---------------- one streaming convert: weights + activations --------------
// i in [0, 7*2^20) float4-chunks: [0,2^20) = 4 weight mats -> wb contiguous;
// [2^20, 7*2^20) = q,k,v acts (2^21 each) -> qb,kb,vb.
__global__ void cvt_all(const float* __restrict__ q, const float* __restrict__ k,
                        const float* __restrict__ v,
                        const float* __restrict__ Wq_, const float* __restrict__ Wk_,
                        const float* __restrict__ Wv_, const float* __restrict__ Wo_,
                        u16* __restrict__ qb, u16* __restrict__ kb,
                        u16* __restrict__ vb, u16* __restrict__ wb) {
  const int i = blockIdx.x * blockDim.x + threadIdx.x;
  float4 f;
  ushort4 o;
  if (i < (1 << 20)) {
    const int s = i >> 18, off = i & 0x3FFFF;
    const float* src = s == 0 ? Wq_ : s == 1 ? Wk_ : s == 2 ? Wv_ : Wo_;
    f = ((const float4*)src)[off];
    o.x = f2b(f.x); o.y = f2b(f.y); o.z = f2b(f.z); o.w = f2b(f.w);
    ((ushort4*)wb)[i] = o;
  } else {
    const int j = i - (1 << 20);
    const int s = j >> 21, off = j & 0x1FFFFF;
    const float* src = s == 0 ? q : s == 1 ? k : v;
    u16* dst = s == 0 ? qb : s == 1 ? kb : vb;
    f = ((const float4*)src)[off];
    o.x = f2b(f.x); o.y = f2b(f.y); o.z = f2b(f.z); o.w = f2b(f.w);
    ((ushort4*)dst)[off] = o;
  }
}

// ---------------- epilogues ----------------
template<int MODE>
__device__ __forceinline__ void gemm_epilogue(
    f4 (&acc)[4][4], const float* __restrict__ bias, void* __restrict__ Cout,
    int N, float scale, int m0, int n0, int wm, int wn, int lr, int lg)
{
  if (MODE == 0) {
    float bv[4];
    #pragma unroll
    for (int j = 0; j < 4; ++j) bv[j] = bias[n0 + wn + j * 16 + lr];
    float* C = (float*)Cout;
    #pragma unroll
    for (int i = 0; i < 4; ++i)
      #pragma unroll
      for (int j = 0; j < 4; ++j) {
        const int col = n0 + wn + j * 16 + lr;
        #pragma unroll
        for (int r = 0; r < 4; ++r) {
          const int row = m0 + wm + i * 16 + lg * 4 + r;
          C[(size_t)row * N + col] = acc[i][j][r] + bv[j];
        }
      }
  } else if (MODE == 1) {
    float bv[4];
    #pragma unroll
    for (int j = 0; j < 4; ++j) bv[j] = bias[n0 + wn + j * 16 + lr];
    u16* C = (u16*)Cout;
    #pragma unroll
    for (int i = 0; i < 4; ++i)
      #pragma unroll
      for (int j = 0; j < 4; ++j) {
        const int col = n0 + wn + j * 16 + lr;     // n = h*64+ch
        const int h = col >> 6, ch = col & 63;
        #pragma unroll
        for (int r = 0; r < 4; ++r) {
          const int row = m0 + wm + i * 16 + lg * 4 + r;  // m = b*2048+t
          const int b = row >> 11, t = row & 2047;
          C[((size_t)(b * 16 + h) * 2048 + t) * 64 + ch] = f2b((acc[i][j][r] + bv[j]) * scale);
        }
      }
  } else {
    u16* C = (u16*)Cout;
    #pragma unroll
    for (int i = 0; i < 4; ++i)
      #pragma unroll
      for (int r = 0; r < 4; ++r) {
        const int nch = m0 + wm + i * 16 + lg * 4 + r;
        const float br = bias[nch];
        const int h = nch >> 6, ch = nch & 63;
        #pragma unroll
        for (int j = 0; j < 4; ++j) {
          const int tok = n0 + wn + j * 16 + lr;
          const int b = tok >> 11, t = tok & 2047;
          C[((size_t)((b * 16 + h) * 64 + ch) << 11) + t] = f2b(acc[i][j][r] + br);
        }
      }
  }
}

// ---------------- all-bf16 pipelined GEMM body (R7 gemm_out structure) -------
// A[M,K], B[N,K] bf16; both staged via glds into XOR-swizzled dbuf LDS.
template<int MODE>
__device__ __forceinline__ void gemm_bf16_body(
    u16* __restrict__ aT, u16* __restrict__ bT,
    const u16* __restrict__ A, const u16* __restrict__ B,
    const float* __restrict__ bias, void* __restrict__ Cout,
    int N, int K, float scale, int m0, int n0)
{
  const int tid = threadIdx.x, lane = tid & 63, w = tid >> 6;
  const int wm = (w >> 1) << 6, wn = (w & 1) << 6;
  const int lr = lane & 15, lg = lane >> 4;

  f4 acc[4][4] = {};

  #define AB_STAGE(buf, karg)                                                   \
    do {                                                                        \
      const int k_ = (karg);                                                    \
      u16* da = aT + ((buf) << 13);                                             \
      u16* db = bT + ((buf) << 13);                                             \
      _Pragma("unroll")                                                         \
      for (int q = 0; q < 4; ++q) {                                             \
        const int c = (w << 8) + (q << 6) + lane;                               \
        const int row = c >> 3, sw = ((c & 7) ^ (row & 7)) << 3;                \
        __builtin_amdgcn_global_load_lds(                                       \
            (const AS1 void*)(A + (size_t)(m0 + row) * K + k_ + sw),            \
            (AS3 void*)(da + (((w << 2) + q) << 9)), 16, 0, 0);                 \
        __builtin_amdgcn_global_load_lds(                                       \
            (const AS1 void*)(B + (size_t)(n0 + row) * K + k_ + sw),            \
            (AS3 void*)(db + (((w << 2) + q) << 9)), 16, 0, 0);                 \
      }                                                                         \
    } while (0)

  AB_STAGE(0, 0);
  __syncthreads();

  const int NKT = K >> 6;
  for (int kt = 0; kt < NKT; ++kt) {
    const int cur = kt & 1;
    const u16* aC = aT + (cur << 13);
    const u16* bC = bT + (cur << 13);
    if (kt + 1 < NKT) AB_STAGE(cur ^ 1, (kt + 1) << 6);

    #pragma unroll
    for (int ks = 0; ks < 2; ++ks) {
      bf8 af[4], bfr[4];
      #pragma unroll
      for (int i = 0; i < 4; ++i) {
        const int ra = wm + i * 16 + lr;
        const int rb = wn + i * 16 + lr;
        af[i]  = *(const bf8*)(aC + (ra << 6) + ((((ks << 2) + lg) ^ (ra & 7)) << 3));
        bfr[i] = *(const bf8*)(bC + (rb << 6) + ((((ks << 2) + lg) ^ (rb & 7)) << 3));
      }
      __builtin_amdgcn_s_setprio(1);
      #pragma unroll
      for (int i = 0; i < 4; ++i)
        #pragma unroll
        for (int j = 0; j < 4; ++j)
          acc[i][j] = __builtin_amdgcn_mfma_f32_16x16x32_bf16(af[i], bfr[j], acc[i][j], 0, 0, 0);
      __builtin_amdgcn_s_setprio(0);
    }
    __syncthreads();
  }
  #undef AB_STAGE

  gemm_epilogue<MODE>(acc, bias, Cout, N, scale, m0, n0, wm, wn, lr, lg);
}

// ---------------- merged QKV projection dispatch (1536 blocks, all-bf16) -----
__global__ __launch_bounds__(256, 2)
void proj_qkv(const u16* __restrict__ qb, const u16* __restrict__ kb,
              const u16* __restrict__ vb,
              const u16* __restrict__ Wq, const u16* __restrict__ Wk,
              const u16* __restrict__ Wv,
              const float* __restrict__ bq, const float* __restrict__ bk,
              const float* __restrict__ bv,
              u16* __restrict__ Qp, u16* __restrict__ Kp, u16* __restrict__ Vt,
              float qscale)
{
  __shared__ __align__(16) u16 pool[32768];     // 64 KB: aT[2][8192] | bT[2][8192]
  u16* const aT = pool;
  u16* const bT = pool + 16384;

  const int cpx = gridDim.x >> 3;
  const int bid = (blockIdx.x & 7) * cpx + (blockIdx.x >> 3);
  const int which = bid >> 9, sub = bid & 511;

  if (which < 2) {
    // Q/K proj: A = tokens (64 m-panels), B = weights (8 n-panels, fastest)
    gemm_bf16_body<1>(aT, bT,
                      which ? kb : qb,
                      which ? Wk : Wq,
                      which ? bk : bq,
                      which ? (void*)Kp : (void*)Qp,
                      1024, 1024, which ? 1.f : qscale,
                      (sub >> 3) << 7, (sub & 7) << 7);
  } else {
    // V proj: A = weights (8 m-panels, fastest), B = tokens (64 n-panels)
    gemm_bf16_body<2>(aT, bT, Wv, vb, bv, (void*)Vt,
                      8192, 1024, 1.f, (sub & 7) << 7, (sub >> 3) << 7);
  }
}

// ---------------- output projection ----------------
__global__ __launch_bounds__(256, 2)
void gemm_out(const u16* __restrict__ A, const u16* __restrict__ B,
              const float* __restrict__ bias, float* __restrict__ C)
{
  __shared__ __align__(16) u16 pool[32768];     // aT[2][8192] | bT[2][8192]
  u16* const aT = pool;
  u16* const bT = pool + 16384;

  const int cpx = gridDim.x >> 3;
  const int bid = (blockIdx.x & 7) * cpx + (blockIdx.x >> 3);
  gemm_bf16_body<0>(aT, bT, A, B, bias, (void*)C, 1024, 1024, 1.f,
                    (bid >> 3) << 7, (bid & 7) << 7);
}

// ---------------- flash attention: 3-buffer counted-vmcnt pipeline (R9) ------
__global__ __launch_bounds__(256, 3)
void attn_kernel(const u16* __restrict__ Qp, const u16* __restrict__ Kp,
                 const u16* __restrict__ VT, u16* __restrict__ Ob)
{
  __shared__ __align__(16) u16 pool[24576];     // 48 KB: kt[3][4096] | vt[3][4096]
  u16* const ktb = pool;
  u16* const vtb = pool + 12288;

  const int flat = blockIdx.x;
  const int xcd = flat & 7, idx = flat >> 3;
  const int bh = (xcd << 3) + (idx >> 4);
  const int tq0 = (idx & 15) << 7;

  const int tid = threadIdx.x, lane = tid & 63, w = tid >> 6;
  const int ql = lane & 31, hi = lane >> 5;
  const size_t hoff = (size_t)bh * (2048 * 64);
  const u16* Kh = Kp + hoff;
  const u16* Vh = VT + hoff;

  bf8 qf[4];
  {
    const u16* qp_ = Qp + hoff + (size_t)(tq0 + w * 32 + ql) * 64 + hi * 8;
    #pragma unroll
    for (int ks = 0; ks < 4; ++ks) qf[ks] = *(const bf8*)(qp_ + 16 * ks);
  }

  f16v o0 = {}, o1 = {};
  float lrun = 0.f;

  const int c0i = (w << 7) + lane;
  const int c1i = c0i + 64;
  const int sr0 = c0i >> 3, ss0 = ((c0i & 7) ^ (sr0 & 7)) << 3;
  const int sr1 = c1i >> 3, ss1 = ((c1i & 7) ^ (sr1 & 7)) << 3;
  const int sd0 = (w << 10);
  const int sd1 = (w << 10) + 512;

  #define STAGE(buf, t0)                                                          \
    do {                                                                           \
      __builtin_amdgcn_global_load_lds((const AS1 void*)(Kh + (size_t)((t0) + sr0) * 64 + ss0), \
                                       (AS3 void*)(ktb + (buf) * 4096 + sd0), 16, 0, 0);  \
      __builtin_amdgcn_global_load_lds((const AS1 void*)(Kh + (size_t)((t0) + sr1) * 64 + ss1), \
                                       (AS3 void*)(ktb + (buf) * 4096 + sd1), 16, 0, 0);  \
      __builtin_amdgcn_global_load_lds((const AS1 void*)(Vh + (size_t)sr0 * 2048 + (t0) + ss0), \
                                       (AS3 void*)(vtb + (buf) * 4096 + sd0), 16, 0, 0);  \
      __builtin_amdgcn_global_load_lds((const AS1 void*)(Vh + (size_t)sr1 * 2048 + (t0) + ss1), \
                                       (AS3 void*)(vtb + (buf) * 4096 + sd1), 16, 0, 0);  \
    } while (0)

  STAGE(0, 0);
  STAGE(1, 64);

  const int xq = ql & 7;
  int bc = 0;
  for (int it = 0; it < 32; ++it) {
    if (it < 31) asm volatile("s_waitcnt vmcnt(4)" ::: "memory");
    else         asm volatile("s_waitcnt vmcnt(0)" ::: "memory");
    __builtin_amdgcn_s_barrier();
    __builtin_amdgcn_sched_barrier(0);

    if (it + 2 < 32) {
      const int bs = bc ? bc - 1 : 2;
      STAGE(bs, (it + 2) << 6);
    }

    const u16* kb = ktb + bc * 4096;
    const u16* vb = vtb + bc * 4096;

    f16v s0 = {}, s1 = {};
    #pragma unroll
    for (int ks = 0; ks < 4; ++ks) {
      bf8 kf0 = *(const bf8*)(kb + (ql << 6) + ((((ks << 1) + hi) ^ xq) << 3));
      bf8 kf1 = *(const bf8*)(kb + ((32 + ql) << 6) + ((((ks << 1) + hi) ^ xq) << 3));
      __builtin_amdgcn_s_setprio(1);
      s0 = __builtin_amdgcn_mfma_f32_32x32x16_bf16(kf0, qf[ks], s0, 0, 0, 0);
      s1 = __builtin_amdgcn_mfma_f32_32x32x16_bf16(kf1, qf[ks], s1, 0, 0, 0);
      __builtin_amdgcn_s_setprio(0);
    }

    bf8 vf0[4], vf1[4];
    #pragma unroll
    for (int ks = 0; ks < 4; ++ks) {
      vf0[ks] = *(const bf8*)(vb + (ql << 6) + ((((ks << 1) + hi) ^ xq) << 3));
      vf1[ks] = *(const bf8*)(vb + ((32 + ql) << 6) + ((((ks << 1) + hi) ^ xq) << 3));
    }

    float rs = 0.f;

    {
      unsigned wpk[8];
      #pragma unroll
      for (int i = 0; i < 8; ++i) {
        float e0 = __builtin_amdgcn_exp2f(s0[2 * i]);
        float e1 = __builtin_amdgcn_exp2f(s0[2 * i + 1]);
        rs += e0 + e1;
        wpk[i] = cvtpk(e0, e1);
      }
      swap32(wpk[0], wpk[2]); swap32(wpk[1], wpk[3]);
      swap32(wpk[4], wpk[6]); swap32(wpk[5], wpk[7]);
      bf8 pf0 = __builtin_bit_cast(bf8, make_uint4(wpk[0], wpk[1], wpk[2], wpk[3]));
      bf8 pf1 = __builtin_bit_cast(bf8, make_uint4(wpk[4], wpk[5], wpk[6], wpk[7]));
      __builtin_amdgcn_s_setprio(1);
      o0 = __builtin_amdgcn_mfma_f32_32x32x16_bf16(vf0[0], pf0, o0, 0, 0, 0);
      o1 = __builtin_amdgcn_mfma_f32_32x32x16_bf16(vf1[0], pf0, o1, 0, 0, 0);
      o0 = __builtin_amdgcn_mfma_f32_32x32x16_bf16(vf0[1], pf1, o0, 0, 0, 0);
      o1 = __builtin_amdgcn_mfma_f32_32x32x16_bf16(vf1[1], pf1, o1, 0, 0, 0);
      __builtin_amdgcn_s_setprio(0);
    }

    {
      unsigned wpk[8];
      #pragma unroll
      for (int i = 0; i < 8; ++i) {
        float e0 = __builtin_amdgcn_exp2f(s1[2 * i]);
        float e1 = __builtin_amdgcn_exp2f(s1[2 * i + 1]);
        rs += e0 + e1;
        wpk[i] = cvtpk(e0, e1);
      }
      swap32(wpk[0], wpk[2]); swap32(wpk[1], wpk[3]);
      swap32(wpk[4], wpk[6]); swap32(wpk[5], wpk[7]);
      bf8 pf2 = __builtin_bit_cast(bf8, make_uint4(wpk[0], wpk[1], wpk[2], wpk[3]));
      bf8 pf3 = __builtin_bit_cast(bf8, make_uint4(wpk[4], wpk[5], wpk[6], wpk[7]));
      __builtin_amdgcn_s_setprio(1);
      o0 = __builtin_amdgcn_mfma_f32_32x32x16_bf16(vf0[2], pf2, o0, 0, 0, 0);
      o1 = __builtin_amdgcn_mfma_f32_32x32x16_bf16(vf1[2], pf2, o1, 0, 0, 0);
      o0 = __builtin_amdgcn_mfma_f32_32x32x16_bf16(vf0[3], pf3, o0, 0, 0, 0);
      o1 = __builtin_amdgcn_mfma_f32_32x32x16_bf16(vf1[3], pf3, o1, 0, 0, 0);
      __builtin_amdgcn_s_setprio(0);
    }

    lrun += rs;
    bc = bc + 1 < 3 ? bc + 1 : 0;
  }
  #undef STAGE

  const float linv = 1.f / (lrun + __shfl_xor(lrun, 32));

  __syncthreads();
  u16* const ot = pool;
  const int orow = w * 32 + ql;
  #pragma unroll
  for (int c = 0; c < 2; ++c) {
    const f16v& o = c ? o1 : o0;
    #pragma unroll
    for (int g = 0; g < 4; ++g) {
      uint2 pk;
      pk.x = cvtpk(o[4 * g + 0] * linv, o[4 * g + 1] * linv);
      pk.y = cvtpk(o[4 * g + 2] * linv, o[4 * g + 3] * linv);
      *(uint2*)(ot + orow * 72 + 32 * c + 8 * g + 4 * hi) = pk;
    }
  }
  __syncthreads();

  const int b = bh >> 4, h = bh & 15;
  const int row = tid >> 1, seg = tid & 1;
  const u16* src = ot + row * 72 + seg * 32;
  u16* dst = Ob + ((size_t)(b * 2048 + tq0 + row) * 16 + h) * 64 + seg * 32;
  #pragma unroll
  for (int kk = 0; kk < 4; ++kk)
    *(uint4*)(dst + 8 * kk) = *(const uint4*)(src + 8 * kk);
}

// ---------------- host launch ----------------
extern "C" void kernel_launch(void* const* d_in, const int* in_sizes, int n_in,
                              void* d_out, int out_size, void* d_ws, size_t ws_size,
                              hipStream_t stream) {
  (void)in_sizes; (void)n_in; (void)out_size; (void)ws_size;
  const float* k_in = (const float*)d_in[0];
  const float* q_in = (const float*)d_in[1];
  const float* v_in = (const float*)d_in[2];
  const float* Wk = (const float*)d_in[3]; const float* bk = (const float*)d_in[4];
  const float* Wq = (const float*)d_in[5]; const float* bq = (const float*)d_in[6];
  const float* Wv = (const float*)d_in[7]; const float* bv = (const float*)d_in[8];
  const float* Wo = (const float*)d_in[9]; const float* bo = (const float*)d_in[10];
  float* out = (float*)d_out;

  char* ws = (char*)d_ws;
  const size_t SZ_ACT = (size_t)8192 * 1024 * 2;   // 16 MB bf16
  const size_t SZ_W   = (size_t)1024 * 1024 * 2;   // 2 MB bf16
  u16* qb  = (u16*)(ws);                            // aliased by Oc after proj
  u16* kb  = (u16*)(ws + 1 * SZ_ACT);
  u16* vb  = (u16*)(ws + 2 * SZ_ACT);
  u16* Qp  = (u16*)(ws + 3 * SZ_ACT);
  u16* Kp  = (u16*)(ws + 4 * SZ_ACT);
  u16* Vt  = (u16*)(ws + 5 * SZ_ACT);               // [B,H,CH,T]
  u16* Wqb = (u16*)(ws + 6 * SZ_ACT);
  u16* Wkb = (u16*)(ws + 6 * SZ_ACT + SZ_W);
  u16* Wvb = (u16*)(ws + 6 * SZ_ACT + 2 * SZ_W);
  u16* Wob = (u16*)(ws + 6 * SZ_ACT + 3 * SZ_W);
  u16* Oc  = qb;                                    // qb dead after proj

  // one streaming convert: weights (contiguous) + q/k/v activations
  cvt_all<<<28672, 256, 0, stream>>>(q_in, k_in, v_in, Wq, Wk, Wv, Wo,
                                     qb, kb, vb, Wqb);

  const float c0 = 0.125f * 1.4426950408889634f;    // softmax scale * log2(e)

  // merged projections (all-bf16): Q (pre-scaled), K -> [B,H,T,CH]; V -> [B,H,CH,T]
  proj_qkv<<<1536, 256, 0, stream>>>(qb, kb, vb, Wqb, Wkb, Wvb,
                                     bq, bk, bv, Qp, Kp, Vt, c0);

  // flash attention -> [B,T,C] bf16
  attn_kernel<<<1024, 256, 0, stream>>>(Qp, Kp, Vt, Oc);

  // output projection -> fp32
  gemm_out<<<512, 256, 0, stream>>>(Oc, Wob, bo, out);
}

// Round 15
// 182.580 us; speedup vs baseline: 1.0321x; 1.0321x over previous
//
#include <hip/hip_runtime.h>

// ---------------------------------------------------------------------------
// Attention block: out = (softmax((q Wq^T+bq)(k Wk^T+bk)^T / 8) (v Wv^T+bv)) Wo^T + bo
// B=4 T=2048 C=1024 H=16 CH=64.  Internal compute bf16 MFMA + f32 accum.
// R14: proj/gemm_out/cvt reverted to R10 (best).  Attn: 8-wave blocks
//      (256 q-rows, 512 threads) -> grid 512 = exactly 2 blocks/CU, 16
//      waves/CU; staging 2 glds/thread, vmcnt(2) counted pipeline.
// ---------------------------------------------------------------------------

typedef short bf8 __attribute__((ext_vector_type(8)));      // 8 bf16 (4 VGPRs)
typedef float f4 __attribute__((ext_vector_type(4)));
typedef float f16v __attribute__((ext_vector_type(16)));
typedef unsigned short u16;

#define AS1 __attribute__((address_space(1)))
#define AS3 __attribute__((address_space(3)))

__device__ __forceinline__ u16 f2b(float f) {
  unsigned u = __builtin_bit_cast(unsigned, f);
  u += 0x7FFFu + ((u >> 16) & 1u);          // RNE
  return (u16)(u >> 16);
}

__device__ __forceinline__ unsigned cvtpk(float lo, float hi) {
  unsigned r;
  asm("v_cvt_pk_bf16_f32 %0, %1, %2" : "=v"(r) : "v"(lo), "v"(hi));
  return r;
}

__device__ __forceinline__ void swap32(unsigned& a, unsigned& b) {
  asm("v_permlane32_swap_b32 %0, %1" : "+v"(a), "+v"(b));
}

// ---------------- fused weight converts (4 x 1024x1024 fp32 -> bf16) --------
__global__ void cvt4_kernel(const float* __restrict__ a, const float* __restrict__ b,
                            const float* __restrict__ c, const float* __restrict__ d,
                            u16* __restrict__ out) {
  int i = blockIdx.x * blockDim.x + threadIdx.x;     // i in [0, 4*2^18)
  const int sel = i >> 18, off = i & 0x3FFFF;
  const float* src = sel == 0 ? a : sel == 1 ? b : sel == 2 ? c : d;
  float4 f = ((const float4*)src)[off];
  ushort4 o;
  o.x = f2b(f.x); o.y = f2b(f.y); o.z = f2b(f.z); o.w = f2b(f.w);
  ((ushort4*)out)[i] = o;
}

// ---------------- epilogues ----------------
template<int MODE>
__device__ __forceinline__ void gemm_epilogue(
    f4 (&acc)[4][4], const float* __restrict__ bias, void* __restrict__ Cout,
    int N, float scale, int m0, int n0, int wm, int wn, int lr, int lg)
{
  if (MODE == 0) {
    float bv[4];
    #pragma unroll
    for (int j = 0; j < 4; ++j) bv[j] = bias[n0 + wn + j * 16 + lr];
    float* C = (float*)Cout;
    #pragma unroll
    for (int i = 0; i < 4; ++i)
      #pragma unroll
      for (int j = 0; j < 4; ++j) {
        const int col = n0 + wn + j * 16 + lr;
        #pragma unroll
        for (int r = 0; r < 4; ++r) {
          const int row = m0 + wm + i * 16 + lg * 4 + r;
          C[(size_t)row * N + col] = acc[i][j][r] + bv[j];
        }
      }
  } else if (MODE == 1) {
    float bv[4];
    #pragma unroll
    for (int j = 0; j < 4; ++j) bv[j] = bias[n0 + wn + j * 16 + lr];
    u16* C = (u16*)Cout;
    #pragma unroll
    for (int i = 0; i < 4; ++i)
      #pragma unroll
      for (int j = 0; j < 4; ++j) {
        const int col = n0 + wn + j * 16 + lr;     // n = h*64+ch
        const int h = col >> 6, ch = col & 63;
        #pragma unroll
        for (int r = 0; r < 4; ++r) {
          const int row = m0 + wm + i * 16 + lg * 4 + r;  // m = b*2048+t
          const int b = row >> 11, t = row & 2047;
          C[((size_t)(b * 16 + h) * 2048 + t) * 64 + ch] = f2b((acc[i][j][r] + bv[j]) * scale);
        }
      }
  } else {
    u16* C = (u16*)Cout;
    #pragma unroll
    for (int i = 0; i < 4; ++i)
      #pragma unroll
      for (int r = 0; r < 4; ++r) {
        const int nch = m0 + wm + i * 16 + lg * 4 + r;
        const float br = bias[nch];
        const int h = nch >> 6, ch = nch & 63;
        #pragma unroll
        for (int j = 0; j < 4; ++j) {
          const int tok = n0 + wn + j * 16 + lr;
          const int b = tok >> 11, t = tok & 2047;
          C[((size_t)((b * 16 + h) * 64 + ch) << 11) + t] = f2b(acc[i][j][r] + br);
        }
      }
  }
}

// ---------------- counted-vmcnt pipelined fp-act GEMM body (R10) ------------
template<int MODE, int ACTB>
__device__ __forceinline__ void gemm_fp_body(
    u16* __restrict__ actT, u16* __restrict__ wT,
    const float* __restrict__ act, const u16* __restrict__ Wt,
    const float* __restrict__ bias, void* __restrict__ Cout,
    int N, int K, float scale, int m0, int n0)
{
  const int tid = threadIdx.x, lane = tid & 63, w = tid >> 6;
  const int wm = (w >> 1) << 6, wn = (w & 1) << 6;
  const int lr = lane & 15, lg = lane >> 4;
  const int arow0 = (ACTB ? n0 : m0);
  const int wrow0 = (ACTB ? m0 : n0);

  f4 acc[4][4] = {};
  float4 ta[8];

  #define W_GLDS(buf, karg)                                                     \
    do {                                                                        \
      const int k_ = (karg);                                                    \
      u16* dst = wT + ((buf) << 13);                                            \
      _Pragma("unroll")                                                         \
      for (int q = 0; q < 4; ++q) {                                             \
        const int c = (w << 8) + (q << 6) + lane;                               \
        const int row = c >> 3, sw = ((c & 7) ^ (row & 7)) << 3;                \
        __builtin_amdgcn_global_load_lds(                                       \
            (const AS1 void*)(Wt + (size_t)(wrow0 + row) * K + k_ + sw),        \
            (AS3 void*)(dst + (((w << 2) + q) << 9)), 16, 0, 0);                \
      }                                                                         \
    } while (0)

  #define ACT_LOAD(karg)                                                        \
    do {                                                                        \
      const int k_ = (karg);                                                    \
      _Pragma("unroll")                                                         \
      for (int q = 0; q < 4; ++q) {                                             \
        const int c = (w << 8) + (q << 6) + lane;                               \
        const int row = c >> 3, col = (c & 7) << 3;                             \
        const float* s = act + (size_t)(arow0 + row) * K + k_ + col;            \
        ta[2 * q] = *(const float4*)s;                                          \
        ta[2 * q + 1] = *(const float4*)(s + 4);                                \
      }                                                                         \
    } while (0)

  #define ACT_WRITE(buf)                                                        \
    do {                                                                        \
      u16* dst = actT + ((buf) << 13);                                          \
      _Pragma("unroll")                                                         \
      for (int q = 0; q < 4; ++q) {                                             \
        const int c = (w << 8) + (q << 6) + lane;                               \
        const int row = c >> 3;                                                 \
        uint4 pk;                                                               \
        pk.x = cvtpk(ta[2 * q].x, ta[2 * q].y);                                 \
        pk.y = cvtpk(ta[2 * q].z, ta[2 * q].w);                                 \
        pk.z = cvtpk(ta[2 * q + 1].x, ta[2 * q + 1].y);                         \
        pk.w = cvtpk(ta[2 * q + 1].z, ta[2 * q + 1].w);                         \
        *(uint4*)(dst + (row << 6) + (((c & 7) ^ (row & 7)) << 3)) = pk;        \
      }                                                                         \
    } while (0)

  // prologue
  W_GLDS(0, 0);
  ACT_LOAD(0);
  ACT_WRITE(0);
  ACT_LOAD(64);
  asm volatile("s_waitcnt lgkmcnt(0)" ::: "memory");

  const int NKT = K >> 6;
  for (int kt = 0; kt < NKT; ++kt) {
    const int cur = kt & 1;
    if (kt > 0) {
      if (kt + 1 < NKT) asm volatile("s_waitcnt vmcnt(8)" ::: "memory");
      else              asm volatile("s_waitcnt vmcnt(0)" ::: "memory");
    }
    __builtin_amdgcn_s_barrier();
    __builtin_amdgcn_sched_barrier(0);

    if (kt + 1 < NKT) W_GLDS(cur ^ 1, (kt + 1) << 6);

    const u16* aC = actT + (cur << 13);
    const u16* wC = wT + (cur << 13);
    #pragma unroll
    for (int ks = 0; ks < 2; ++ks) {
      bf8 af[4], bfr[4];
      #pragma unroll
      for (int i = 0; i < 4; ++i) {
        const int ra = wm + i * 16 + lr;
        const int rb = wn + i * 16 + lr;
        const u16* aSrc = ACTB ? wC : aC;
        const u16* bSrc = ACTB ? aC : wC;
        af[i]  = *(const bf8*)(aSrc + (ra << 6) + ((((ks << 2) + lg) ^ (ra & 7)) << 3));
        bfr[i] = *(const bf8*)(bSrc + (rb << 6) + ((((ks << 2) + lg) ^ (rb & 7)) << 3));
      }
      __builtin_amdgcn_s_setprio(1);
      #pragma unroll
      for (int i = 0; i < 4; ++i)
        #pragma unroll
        for (int j = 0; j < 4; ++j)
          acc[i][j] = __builtin_amdgcn_mfma_f32_16x16x32_bf16(af[i], bfr[j], acc[i][j], 0, 0, 0);
      __builtin_amdgcn_s_setprio(0);
    }

    if (kt + 1 < NKT) {
      ACT_WRITE(cur ^ 1);
      if (kt + 2 < NKT) ACT_LOAD((kt + 2) << 6);
    }
    asm volatile("s_waitcnt lgkmcnt(0)" ::: "memory");
  }
  #undef W_GLDS
  #undef ACT_LOAD
  #undef ACT_WRITE

  gemm_epilogue<MODE>(acc, bias, Cout, N, scale, m0, n0, wm, wn, lr, lg);
}

// ---------------- merged QKV projection dispatch (1536 blocks) ----------------
__global__ __launch_bounds__(256, 2)
void proj_qkv(const float* __restrict__ q_in, const float* __restrict__ k_in,
              const float* __restrict__ v_in,
              const u16* __restrict__ Wq, const u16* __restrict__ Wk,
              const u16* __restrict__ Wv,
              const float* __restrict__ bq, const float* __restrict__ bk,
              const float* __restrict__ bv,
              u16* __restrict__ Qp, u16* __restrict__ Kp, u16* __restrict__ Vt,
              float qscale)
{
  __shared__ __align__(16) u16 pool[32768];     // 64 KB: actT[2][8192] | wT[2][8192]
  u16* const actT = pool;
  u16* const wT   = pool + 16384;

  const int cpx = gridDim.x >> 3;
  const int bid = (blockIdx.x & 7) * cpx + (blockIdx.x >> 3);
  const int which = bid >> 9, sub = bid & 511;

  if (which < 2) {
    gemm_fp_body<1, 0>(actT, wT,
                       which ? k_in : q_in,
                       which ? Wk : Wq,
                       which ? bk : bq,
                       which ? (void*)Kp : (void*)Qp,
                       1024, 1024, which ? 1.f : qscale,
                       (sub >> 3) << 7, (sub & 7) << 7);
  } else {
    gemm_fp_body<2, 1>(actT, wT, v_in, Wv, bv, (void*)Vt,
                       8192, 1024, 1.f, (sub & 7) << 7, (sub >> 3) << 7);
  }
}

// ---------------- output projection (all-bf16, pipelined, R7) ----------------
__global__ __launch_bounds__(256, 2)
void gemm_out(const u16* __restrict__ A, const u16* __restrict__ B,
              const float* __restrict__ bias, float* __restrict__ C)
{
  __shared__ __align__(16) u16 pool[32768];     // aT[2][8192] | bT[2][8192]
  u16* const aT = pool;
  u16* const bT = pool + 16384;

  const int cpx = gridDim.x >> 3;
  const int bid = (blockIdx.x & 7) * cpx + (blockIdx.x >> 3);
  const int m0 = (bid >> 3) << 7, n0 = (bid & 7) << 7;
  const int tid = threadIdx.x, lane = tid & 63, w = tid >> 6;
  const int wm = (w >> 1) << 6, wn = (w & 1) << 6;
  const int lr = lane & 15, lg = lane >> 4;
  const int K = 1024;

  f4 acc[4][4] = {};

  #pragma unroll
  for (int q = 0; q < 4; ++q) {
    const int c = (w << 8) + (q << 6) + lane;
    const int row = c >> 3, sw = ((c & 7) ^ (row & 7)) << 3;
    __builtin_amdgcn_global_load_lds(
        (const AS1 void*)(A + (size_t)(m0 + row) * K + sw),
        (AS3 void*)(aT + (((w << 2) + q) << 9)), 16, 0, 0);
    __builtin_amdgcn_global_load_lds(
        (const AS1 void*)(B + (size_t)(n0 + row) * K + sw),
        (AS3 void*)(bT + (((w << 2) + q) << 9)), 16, 0, 0);
  }
  __syncthreads();

  for (int kt = 0; kt < 16; ++kt) {
    const int cur = kt & 1;
    const u16* aC = aT + (cur << 13);
    const u16* bC = bT + (cur << 13);
    if (kt + 1 < 16) {
      u16* aN = aT + ((cur ^ 1) << 13);
      u16* bN = bT + ((cur ^ 1) << 13);
      const int k1 = (kt + 1) << 6;
      #pragma unroll
      for (int q = 0; q < 4; ++q) {
        const int c = (w << 8) + (q << 6) + lane;
        const int row = c >> 3, sw = ((c & 7) ^ (row & 7)) << 3;
        __builtin_amdgcn_global_load_lds(
            (const AS1 void*)(A + (size_t)(m0 + row) * K + k1 + sw),
            (AS3 void*)(aN + (((w << 2) + q) << 9)), 16, 0, 0);
        __builtin_amdgcn_global_load_lds(
            (const AS1 void*)(B + (size_t)(n0 + row) * K + k1 + sw),
            (AS3 void*)(bN + (((w << 2) + q) << 9)), 16, 0, 0);
      }
    }
    #pragma unroll
    for (int ks = 0; ks < 2; ++ks) {
      bf8 af[4], bfr[4];
      #pragma unroll
      for (int i = 0; i < 4; ++i) {
        const int ra = wm + i * 16 + lr;
        const int rb = wn + i * 16 + lr;
        af[i]  = *(const bf8*)(aC + (ra << 6) + ((((ks << 2) + lg) ^ (ra & 7)) << 3));
        bfr[i] = *(const bf8*)(bC + (rb << 6) + ((((ks << 2) + lg) ^ (rb & 7)) << 3));
      }
      __builtin_amdgcn_s_setprio(1);
      #pragma unroll
      for (int i = 0; i < 4; ++i)
        #pragma unroll
        for (int j = 0; j < 4; ++j)
          acc[i][j] = __builtin_amdgcn_mfma_f32_16x16x32_bf16(af[i], bfr[j], acc[i][j], 0, 0, 0);
      __builtin_amdgcn_s_setprio(0);
    }
    __syncthreads();
  }

  gemm_epilogue<0>(acc, bias, (void*)C, 1024, 1.f, m0, n0, wm, wn, lr, lg);
}

// ---------------- flash attention: 8-wave blocks, 3-buf counted vmcnt --------
// grid 512 (= exactly 2 blocks/CU), 512 threads = 8 waves x 32 q (256 q-rows).
// Q (pre-scaled), K in [B,H,T,CH]; V^T in [B,H,CH,T]; O in [B,T,C] bf16.
// Staging: 2 glds/thread/tile (1 K + 1 V); 2-tile-ahead; vmcnt(2) at loop top.
__global__ __launch_bounds__(512, 2)
void attn_kernel(const u16* __restrict__ Qp, const u16* __restrict__ Kp,
                 const u16* __restrict__ VT, u16* __restrict__ Ob)
{
  __shared__ __align__(16) u16 pool[24576];     // 48 KB: kt[3][4096] | vt[3][4096]; ot[256][72] reuse
  u16* const ktb = pool;
  u16* const vtb = pool + 12288;

  const int flat = blockIdx.x;                  // 512 blocks: 8 XCD x (8 bh x 8 qtiles)
  const int xcd = flat & 7, idx = flat >> 3;
  const int bh = (xcd << 3) + (idx >> 3);
  const int tq0 = (idx & 7) << 8;

  const int tid = threadIdx.x, lane = tid & 63, w = tid >> 6;
  const int ql = lane & 31, hi = lane >> 5;
  const size_t hoff = (size_t)bh * (2048 * 64);
  const u16* Kh = Kp + hoff;
  const u16* Vh = VT + hoff;

  bf8 qf[4];
  {
    const u16* qp_ = Qp + hoff + (size_t)(tq0 + w * 32 + ql) * 64 + hi * 8;
    #pragma unroll
    for (int ks = 0; ks < 4; ++ks) qf[ks] = *(const bf8*)(qp_ + 16 * ks);
  }

  f16v o0 = {}, o1 = {};
  float lrun = 0.f;

  // staging: chunk id = tid (512 chunks of 16B per 8KB tile)
  const int sr0 = tid >> 3;                       // row 0..63
  const int ss0 = ((tid & 7) ^ (sr0 & 7)) << 3;   // pre-swizzled src chunk (u16)
  const int sd0 = tid << 3;                       // dest u16 offset

  #define STAGE(buf, t0)                                                          \
    do {                                                                           \
      __builtin_amdgcn_global_load_lds((const AS1 void*)(Kh + (size_t)((t0) + sr0) * 64 + ss0), \
                                       (AS3 void*)(ktb + (buf) * 4096 + sd0), 16, 0, 0);  \
      __builtin_amdgcn_global_load_lds((const AS1 void*)(Vh + (size_t)sr0 * 2048 + (t0) + ss0), \
                                       (AS3 void*)(vtb + (buf) * 4096 + sd0), 16, 0, 0);  \
    } while (0)

  STAGE(0, 0);
  STAGE(1, 64);

  const int xq = ql & 7;
  int bc = 0;
  for (int it = 0; it < 32; ++it) {
    if (it < 31) asm volatile("s_waitcnt vmcnt(2)" ::: "memory");
    else         asm volatile("s_waitcnt vmcnt(0)" ::: "memory");
    __builtin_amdgcn_s_barrier();
    __builtin_amdgcn_sched_barrier(0);

    if (it + 2 < 32) {
      const int bs = bc ? bc - 1 : 2;             // (bc+2)%3
      STAGE(bs, (it + 2) << 6);
    }

    const u16* kb = ktb + bc * 4096;
    const u16* vb = vtb + bc * 4096;

    // S^T = K Q^T : s0 -> tk 0-31, s1 -> tk 32-63
    f16v s0 = {}, s1 = {};
    #pragma unroll
    for (int ks = 0; ks < 4; ++ks) {
      bf8 kf0 = *(const bf8*)(kb + (ql << 6) + ((((ks << 1) + hi) ^ xq) << 3));
      bf8 kf1 = *(const bf8*)(kb + ((32 + ql) << 6) + ((((ks << 1) + hi) ^ xq) << 3));
      __builtin_amdgcn_s_setprio(1);
      s0 = __builtin_amdgcn_mfma_f32_32x32x16_bf16(kf0, qf[ks], s0, 0, 0, 0);
      s1 = __builtin_amdgcn_mfma_f32_32x32x16_bf16(kf1, qf[ks], s1, 0, 0, 0);
      __builtin_amdgcn_s_setprio(0);
    }

    bf8 vf0[4], vf1[4];
    #pragma unroll
    for (int ks = 0; ks < 4; ++ks) {
      vf0[ks] = *(const bf8*)(vb + (ql << 6) + ((((ks << 1) + hi) ^ xq) << 3));
      vf1[ks] = *(const bf8*)(vb + ((32 + ql) << 6) + ((((ks << 1) + hi) ^ xq) << 3));
    }

    float rs = 0.f;

    {
      unsigned wpk[8];
      #pragma unroll
      for (int i = 0; i < 8; ++i) {
        float e0 = __builtin_amdgcn_exp2f(s0[2 * i]);
        float e1 = __builtin_amdgcn_exp2f(s0[2 * i + 1]);
        rs += e0 + e1;
        wpk[i] = cvtpk(e0, e1);
      }
      swap32(wpk[0], wpk[2]); swap32(wpk[1], wpk[3]);
      swap32(wpk[4], wpk[6]); swap32(wpk[5], wpk[7]);
      bf8 pf0 = __builtin_bit_cast(bf8, make_uint4(wpk[0], wpk[1], wpk[2], wpk[3]));
      bf8 pf1 = __builtin_bit_cast(bf8, make_uint4(wpk[4], wpk[5], wpk[6], wpk[7]));
      __builtin_amdgcn_s_setprio(1);
      o0 = __builtin_amdgcn_mfma_f32_32x32x16_bf16(vf0[0], pf0, o0, 0, 0, 0);
      o1 = __builtin_amdgcn_mfma_f32_32x32x16_bf16(vf1[0], pf0, o1, 0, 0, 0);
      o0 = __builtin_amdgcn_mfma_f32_32x32x16_bf16(vf0[1], pf1, o0, 0, 0, 0);
      o1 = __builtin_amdgcn_mfma_f32_32x32x16_bf16(vf1[1], pf1, o1, 0, 0, 0);
      __builtin_amdgcn_s_setprio(0);
    }

    {
      unsigned wpk[8];
      #pragma unroll
      for (int i = 0; i < 8; ++i) {
        float e0 = __builtin_amdgcn_exp2f(s1[2 * i]);
        float e1 = __builtin_amdgcn_exp2f(s1[2 * i + 1]);
        rs += e0 + e1;
        wpk[i] = cvtpk(e0, e1);
      }
      swap32(wpk[0], wpk[2]); swap32(wpk[1], wpk[3]);
      swap32(wpk[4], wpk[6]); swap32(wpk[5], wpk[7]);
      bf8 pf2 = __builtin_bit_cast(bf8, make_uint4(wpk[0], wpk[1], wpk[2], wpk[3]));
      bf8 pf3 = __builtin_bit_cast(bf8, make_uint4(wpk[4], wpk[5], wpk[6], wpk[7]));
      __builtin_amdgcn_s_setprio(1);
      o0 = __builtin_amdgcn_mfma_f32_32x32x16_bf16(vf0[2], pf2, o0, 0, 0, 0);
      o1 = __builtin_amdgcn_mfma_f32_32x32x16_bf16(vf1[2], pf2, o1, 0, 0, 0);
      o0 = __builtin_amdgcn_mfma_f32_32x32x16_bf16(vf0[3], pf3, o0, 0, 0, 0);
      o1 = __builtin_amdgcn_mfma_f32_32x32x16_bf16(vf1[3], pf3, o1, 0, 0, 0);
      __builtin_amdgcn_s_setprio(0);
    }

    lrun += rs;
    bc = bc + 1 < 3 ? bc + 1 : 0;
  }
  #undef STAGE

  const float linv = 1.f / (lrun + __shfl_xor(lrun, 32));

  __syncthreads();                  // all tile reads done before pool reuse
  u16* const ot = pool;             // ot[256][72]
  const int orow = w * 32 + ql;
  #pragma unroll
  for (int c = 0; c < 2; ++c) {
    const f16v& o = c ? o1 : o0;
    #pragma unroll
    for (int g = 0; g < 4; ++g) {
      uint2 pk;
      pk.x = cvtpk(o[4 * g + 0] * linv, o[4 * g + 1] * linv);
      pk.y = cvtpk(o[4 * g + 2] * linv, o[4 * g + 3] * linv);
      *(uint2*)(ot + orow * 72 + 32 * c + 8 * g + 4 * hi) = pk;
    }
  }
  __syncthreads();

  const int b = bh >> 4, h = bh & 15;
  const int row = tid >> 1, seg = tid & 1;       // 256 rows x 2 segs
  const u16* src = ot + row * 72 + seg * 32;
  u16* dst = Ob + ((size_t)(b * 2048 + tq0 + row) * 16 + h) * 64 + seg * 32;
  #pragma unroll
  for (int kk = 0; kk < 4; ++kk)
    *(uint4*)(dst + 8 * kk) = *(const uint4*)(src + 8 * kk);
}

// ---------------- host launch ----------------
extern "C" void kernel_launch(void* const* d_in, const int* in_sizes, int n_in,
                              void* d_out, int out_size, void* d_ws, size_t ws_size,
                              hipStream_t stream) {
  (void)in_sizes; (void)n_in; (void)out_size; (void)ws_size;
  const float* k_in = (const float*)d_in[0];
  const float* q_in = (const float*)d_in[1];
  const float* v_in = (const float*)d_in[2];
  const float* Wk = (const float*)d_in[3]; const float* bk = (const float*)d_in[4];
  const float* Wq = (const float*)d_in[5]; const float* bq = (const float*)d_in[6];
  const float* Wv = (const float*)d_in[7]; const float* bv = (const float*)d_in[8];
  const float* Wo = (const float*)d_in[9]; const float* bo = (const float*)d_in[10];
  float* out = (float*)d_out;

  char* ws = (char*)d_ws;
  const size_t SZ_ACT = (size_t)8192 * 1024 * 2;   // 16 MB bf16
  const size_t SZ_W   = (size_t)1024 * 1024 * 2;   // 2 MB bf16
  u16* Oc  = (u16*)(ws);
  u16* Qp  = (u16*)(ws + 1 * SZ_ACT);
  u16* Kp  = (u16*)(ws + 2 * SZ_ACT);
  u16* Vt  = (u16*)(ws + 3 * SZ_ACT);               // [B,H,CH,T]
  u16* Wqb = (u16*)(ws + 4 * SZ_ACT);
  u16* Wkb = (u16*)(ws + 4 * SZ_ACT + SZ_W);
  u16* Wvb = (u16*)(ws + 4 * SZ_ACT + 2 * SZ_W);
  u16* Wob = (u16*)(ws + 4 * SZ_ACT + 3 * SZ_W);

  // weights: one fused convert (outputs contiguous Wq|Wk|Wv|Wo)
  cvt4_kernel<<<4096, 256, 0, stream>>>(Wq, Wk, Wv, Wo, Wqb);

  const float c0 = 0.125f * 1.4426950408889634f;    // softmax scale * log2(e)

  // merged projections: Q (pre-scaled), K -> [B,H,T,CH]; V -> [B,H,CH,T]
  proj_qkv<<<1536, 256, 0, stream>>>(q_in, k_in, v_in, Wqb, Wkb, Wvb,
                                     bq, bk, bv, Qp, Kp, Vt, c0);

  // flash attention -> [B,T,C] bf16
  attn_kernel<<<512, 512, 0, stream>>>(Qp, Kp, Vt, Oc);

  // output projection -> fp32
  gemm_out<<<512, 256, 0, stream>>>(Oc, Wob, bo, out);
}

// Round 16
// 177.858 us; speedup vs baseline: 1.0595x; 1.0266x over previous
//
#include <hip/hip_runtime.h>

// ---------------------------------------------------------------------------
// Attention block: out = (softmax((q Wq^T+bq)(k Wk^T+bk)^T / 8) (v Wv^T+bv)) Wo^T + bo
// B=4 T=2048 C=1024 H=16 CH=64.  Internal compute bf16 MFMA + f32 accum.
// R15: proj_qkv -> 512-thread blocks (8 waves, 2x4 wave grid, acc[4][2]) on
//      the same 128^2 tile + counted-vmcnt pipeline: 16 waves/CU (2x TLP).
//      Attn reverted to R9 4-wave (best).  gemm_out/cvt4 unchanged (R10).
// ---------------------------------------------------------------------------

typedef short bf8 __attribute__((ext_vector_type(8)));      // 8 bf16 (4 VGPRs)
typedef float f4 __attribute__((ext_vector_type(4)));
typedef float f16v __attribute__((ext_vector_type(16)));
typedef unsigned short u16;

#define AS1 __attribute__((address_space(1)))
#define AS3 __attribute__((address_space(3)))

__device__ __forceinline__ u16 f2b(float f) {
  unsigned u = __builtin_bit_cast(unsigned, f);
  u += 0x7FFFu + ((u >> 16) & 1u);          // RNE
  return (u16)(u >> 16);
}

__device__ __forceinline__ unsigned cvtpk(float lo, float hi) {
  unsigned r;
  asm("v_cvt_pk_bf16_f32 %0, %1, %2" : "=v"(r) : "v"(lo), "v"(hi));
  return r;
}

__device__ __forceinline__ void swap32(unsigned& a, unsigned& b) {
  asm("v_permlane32_swap_b32 %0, %1" : "+v"(a), "+v"(b));
}

// ---------------- fused weight converts (4 x 1024x1024 fp32 -> bf16) --------
__global__ void cvt4_kernel(const float* __restrict__ a, const float* __restrict__ b,
                            const float* __restrict__ c, const float* __restrict__ d,
                            u16* __restrict__ out) {
  int i = blockIdx.x * blockDim.x + threadIdx.x;     // i in [0, 4*2^18)
  const int sel = i >> 18, off = i & 0x3FFFF;
  const float* src = sel == 0 ? a : sel == 1 ? b : sel == 2 ? c : d;
  float4 f = ((const float4*)src)[off];
  ushort4 o;
  o.x = f2b(f.x); o.y = f2b(f.y); o.z = f2b(f.z); o.w = f2b(f.w);
  ((ushort4*)out)[i] = o;
}

// ---------------- epilogue for 4-wave (acc[4][4]) kernels ----------------
__device__ __forceinline__ void gemm_epilogue44(
    f4 (&acc)[4][4], const float* __restrict__ bias, float* __restrict__ C,
    int N, int m0, int n0, int wm, int wn, int lr, int lg)
{
  float bv[4];
  #pragma unroll
  for (int j = 0; j < 4; ++j) bv[j] = bias[n0 + wn + j * 16 + lr];
  #pragma unroll
  for (int i = 0; i < 4; ++i)
    #pragma unroll
    for (int j = 0; j < 4; ++j) {
      const int col = n0 + wn + j * 16 + lr;
      #pragma unroll
      for (int r = 0; r < 4; ++r) {
        const int row = m0 + wm + i * 16 + lg * 4 + r;
        C[(size_t)row * N + col] = acc[i][j][r] + bv[j];
      }
    }
}

// ---------------- 8-wave counted-vmcnt pipelined fp-act GEMM body ------------
// 512 threads, wave grid 2(m) x 4(n); per-wave acc[4][2] (64 x 32 output).
// ACTB=0: A = fp32 act (m rows), B = bf16 weights.  ACTB=1: A = weights, B = act.
// LDS: actT/wT each 2 x 8192 u16 (128 x 64 tiles), XOR-swizzled (8 chunks/row).
// Per iter kt: [vmcnt(4); barrier] -> glds W(kt+1) [2] -> MFMA(kt) ->
// cvt+ds_write act(kt+1) [waits its 4 loads] -> fp32 load act(kt+2) [4] -> lgkm.
template<int MODE, int ACTB>
__device__ __forceinline__ void gemm_fp_body8(
    u16* __restrict__ actT, u16* __restrict__ wT,
    const float* __restrict__ act, const u16* __restrict__ Wt,
    const float* __restrict__ bias, void* __restrict__ Cout,
    int N, int K, float scale, int m0, int n0)
{
  const int tid = threadIdx.x, lane = tid & 63, w = tid >> 6;   // w 0..7
  const int wm = (w >> 2) << 6;        // 0,64
  const int wn = (w & 3) << 5;         // 0,32,64,96
  const int lr = lane & 15, lg = lane >> 4;
  const int arow0 = (ACTB ? n0 : m0);
  const int wrow0 = (ACTB ? m0 : n0);

  f4 acc[4][2] = {};
  float4 ta[4];

  // chunk ids: c0 = tid (rows 0..63), c1 = tid + 512 (rows 64..127)
  const int r0 = tid >> 3, x0 = tid & 7;
  const int r1 = r0 + 64;
  const int wsw0 = (x0 ^ (r0 & 7)) << 3;      // pre-swizzled src col (u16)
  const int wsw1 = (x0 ^ (r1 & 7)) << 3;

  #define W_GLDS(buf, karg)                                                     \
    do {                                                                        \
      const int k_ = (karg);                                                    \
      u16* dst = wT + ((buf) << 13);                                            \
      __builtin_amdgcn_global_load_lds(                                         \
          (const AS1 void*)(Wt + (size_t)(wrow0 + r0) * K + k_ + wsw0),         \
          (AS3 void*)(dst + (w << 9)), 16, 0, 0);                               \
      __builtin_amdgcn_global_load_lds(                                         \
          (const AS1 void*)(Wt + (size_t)(wrow0 + r1) * K + k_ + wsw1),         \
          (AS3 void*)(dst + 4096 + (w << 9)), 16, 0, 0);                        \
    } while (0)

  #define ACT_LOAD(karg)                                                        \
    do {                                                                        \
      const int k_ = (karg);                                                    \
      const float* s0 = act + (size_t)(arow0 + r0) * K + k_ + (x0 << 3);        \
      const float* s1 = act + (size_t)(arow0 + r1) * K + k_ + (x0 << 3);        \
      ta[0] = *(const float4*)s0; ta[1] = *(const float4*)(s0 + 4);             \
      ta[2] = *(const float4*)s1; ta[3] = *(const float4*)(s1 + 4);             \
    } while (0)

  #define ACT_WRITE(buf)                                                        \
    do {                                                                        \
      u16* dst = actT + ((buf) << 13);                                          \
      uint4 pk0, pk1;                                                           \
      pk0.x = cvtpk(ta[0].x, ta[0].y); pk0.y = cvtpk(ta[0].z, ta[0].w);         \
      pk0.z = cvtpk(ta[1].x, ta[1].y); pk0.w = cvtpk(ta[1].z, ta[1].w);         \
      pk1.x = cvtpk(ta[2].x, ta[2].y); pk1.y = cvtpk(ta[2].z, ta[2].w);         \
      pk1.z = cvtpk(ta[3].x, ta[3].y); pk1.w = cvtpk(ta[3].z, ta[3].w);         \
      *(uint4*)(dst + (r0 << 6) + wsw0) = pk0;                                  \
      *(uint4*)(dst + (r1 << 6) + wsw1) = pk1;                                  \
    } while (0)

  // prologue: glds W(0); act(0)->regs->buf0 (drains all); act(1)->regs
  W_GLDS(0, 0);
  ACT_LOAD(0);
  ACT_WRITE(0);
  ACT_LOAD(64);
  asm volatile("s_waitcnt lgkmcnt(0)" ::: "memory");

  const int NKT = K >> 6;
  for (int kt = 0; kt < NKT; ++kt) {
    const int cur = kt & 1;
    if (kt > 0) {
      if (kt + 1 < NKT) asm volatile("s_waitcnt vmcnt(4)" ::: "memory");
      else              asm volatile("s_waitcnt vmcnt(0)" ::: "memory");
    }
    __builtin_amdgcn_s_barrier();
    __builtin_amdgcn_sched_barrier(0);

    if (kt + 1 < NKT) W_GLDS(cur ^ 1, (kt + 1) << 6);

    const u16* aC = actT + (cur << 13);
    const u16* wC = wT + (cur << 13);
    #pragma unroll
    for (int ks = 0; ks < 2; ++ks) {
      const u16* aSrc = ACTB ? wC : aC;      // A-operand rows = m-tile
      const u16* bSrc = ACTB ? aC : wC;      // B-operand rows = n-tile
      bf8 af[4], bfr[2];
      #pragma unroll
      for (int i = 0; i < 4; ++i) {
        const int ra = wm + i * 16 + lr;
        af[i] = *(const bf8*)(aSrc + (ra << 6) + ((((ks << 2) + lg) ^ (ra & 7)) << 3));
      }
      #pragma unroll
      for (int j = 0; j < 2; ++j) {
        const int rb = wn + j * 16 + lr;
        bfr[j] = *(const bf8*)(bSrc + (rb << 6) + ((((ks << 2) + lg) ^ (rb & 7)) << 3));
      }
      __builtin_amdgcn_s_setprio(1);
      #pragma unroll
      for (int i = 0; i < 4; ++i)
        #pragma unroll
        for (int j = 0; j < 2; ++j)
          acc[i][j] = __builtin_amdgcn_mfma_f32_16x16x32_bf16(af[i], bfr[j], acc[i][j], 0, 0, 0);
      __builtin_amdgcn_s_setprio(0);
    }

    if (kt + 1 < NKT) {
      ACT_WRITE(cur ^ 1);                   // compiler waits act(kt+1) loads (vmcnt(2))
      if (kt + 2 < NKT) ACT_LOAD((kt + 2) << 6);
    }
    asm volatile("s_waitcnt lgkmcnt(0)" ::: "memory");
  }
  #undef W_GLDS
  #undef ACT_LOAD
  #undef ACT_WRITE

  // epilogue (acc[4][2])
  if (MODE == 1) {
    float bv[2];
    #pragma unroll
    for (int j = 0; j < 2; ++j) bv[j] = bias[n0 + wn + j * 16 + lr];
    u16* C = (u16*)Cout;
    #pragma unroll
    for (int i = 0; i < 4; ++i)
      #pragma unroll
      for (int j = 0; j < 2; ++j) {
        const int col = n0 + wn + j * 16 + lr;     // n = h*64+ch
        const int h = col >> 6, ch = col & 63;
        #pragma unroll
        for (int r = 0; r < 4; ++r) {
          const int row = m0 + wm + i * 16 + lg * 4 + r;  // m = b*2048+t
          const int b = row >> 11, t = row & 2047;
          C[((size_t)(b * 16 + h) * 2048 + t) * 64 + ch] = f2b((acc[i][j][r] + bv[j]) * scale);
        }
      }
  } else {
    u16* C = (u16*)Cout;
    #pragma unroll
    for (int i = 0; i < 4; ++i)
      #pragma unroll
      for (int r = 0; r < 4; ++r) {
        const int nch = m0 + wm + i * 16 + lg * 4 + r;     // weight out-channel
        const float br = bias[nch];
        const int h = nch >> 6, ch = nch & 63;
        #pragma unroll
        for (int j = 0; j < 2; ++j) {
          const int tok = n0 + wn + j * 16 + lr;           // b*2048+t
          const int b = tok >> 11, t = tok & 2047;
          C[((size_t)((b * 16 + h) * 64 + ch) << 11) + t] = f2b(acc[i][j][r] + br);
        }
      }
  }
}

// ---------------- merged QKV projection dispatch (1536 blocks x 512 thr) -----
__global__ __launch_bounds__(512, 4)
void proj_qkv(const float* __restrict__ q_in, const float* __restrict__ k_in,
              const float* __restrict__ v_in,
              const u16* __restrict__ Wq, const u16* __restrict__ Wk,
              const u16* __restrict__ Wv,
              const float* __restrict__ bq, const float* __restrict__ bk,
              const float* __restrict__ bv,
              u16* __restrict__ Qp, u16* __restrict__ Kp, u16* __restrict__ Vt,
              float qscale)
{
  __shared__ __align__(16) u16 pool[32768];     // 64 KB: actT[2][8192] | wT[2][8192]
  u16* const actT = pool;
  u16* const wT   = pool + 16384;

  const int cpx = gridDim.x >> 3;
  const int bid = (blockIdx.x & 7) * cpx + (blockIdx.x >> 3);
  const int which = bid >> 9, sub = bid & 511;

  if (which < 2) {
    // Q/K proj: 64 token m-panels x 8 weight n-panels (n fastest -> act L2 reuse)
    gemm_fp_body8<1, 0>(actT, wT,
                        which ? k_in : q_in,
                        which ? Wk : Wq,
                        which ? bk : bq,
                        which ? (void*)Kp : (void*)Qp,
                        1024, 1024, which ? 1.f : qscale,
                        (sub >> 3) << 7, (sub & 7) << 7);
  } else {
    // V proj: 8 weight m-panels (fastest) x 64 token n-panels
    gemm_fp_body8<2, 1>(actT, wT, v_in, Wv, bv, (void*)Vt,
                        8192, 1024, 1.f, (sub & 7) << 7, (sub >> 3) << 7);
  }
}

// ---------------- output projection (all-bf16, pipelined, R7) ----------------
__global__ __launch_bounds__(256, 2)
void gemm_out(const u16* __restrict__ A, const u16* __restrict__ B,
              const float* __restrict__ bias, float* __restrict__ C)
{
  __shared__ __align__(16) u16 pool[32768];     // aT[2][8192] | bT[2][8192]
  u16* const aT = pool;
  u16* const bT = pool + 16384;

  const int cpx = gridDim.x >> 3;
  const int bid = (blockIdx.x & 7) * cpx + (blockIdx.x >> 3);
  const int m0 = (bid >> 3) << 7, n0 = (bid & 7) << 7;
  const int tid = threadIdx.x, lane = tid & 63, w = tid >> 6;
  const int wm = (w >> 1) << 6, wn = (w & 1) << 6;
  const int lr = lane & 15, lg = lane >> 4;
  const int K = 1024;

  f4 acc[4][4] = {};

  #pragma unroll
  for (int q = 0; q < 4; ++q) {
    const int c = (w << 8) + (q << 6) + lane;
    const int row = c >> 3, sw = ((c & 7) ^ (row & 7)) << 3;
    __builtin_amdgcn_global_load_lds(
        (const AS1 void*)(A + (size_t)(m0 + row) * K + sw),
        (AS3 void*)(aT + (((w << 2) + q) << 9)), 16, 0, 0);
    __builtin_amdgcn_global_load_lds(
        (const AS1 void*)(B + (size_t)(n0 + row) * K + sw),
        (AS3 void*)(bT + (((w << 2) + q) << 9)), 16, 0, 0);
  }
  __syncthreads();

  for (int kt = 0; kt < 16; ++kt) {
    const int cur = kt & 1;
    const u16* aC = aT + (cur << 13);
    const u16* bC = bT + (cur << 13);
    if (kt + 1 < 16) {
      u16* aN = aT + ((cur ^ 1) << 13);
      u16* bN = bT + ((cur ^ 1) << 13);
      const int k1 = (kt + 1) << 6;
      #pragma unroll
      for (int q = 0; q < 4; ++q) {
        const int c = (w << 8) + (q << 6) + lane;
        const int row = c >> 3, sw = ((c & 7) ^ (row & 7)) << 3;
        __builtin_amdgcn_global_load_lds(
            (const AS1 void*)(A + (size_t)(m0 + row) * K + k1 + sw),
            (AS3 void*)(aN + (((w << 2) + q) << 9)), 16, 0, 0);
        __builtin_amdgcn_global_load_lds(
            (const AS1 void*)(B + (size_t)(n0 + row) * K + k1 + sw),
            (AS3 void*)(bN + (((w << 2) + q) << 9)), 16, 0, 0);
      }
    }
    #pragma unroll
    for (int ks = 0; ks < 2; ++ks) {
      bf8 af[4], bfr[4];
      #pragma unroll
      for (int i = 0; i < 4; ++i) {
        const int ra = wm + i * 16 + lr;
        const int rb = wn + i * 16 + lr;
        af[i]  = *(const bf8*)(aC + (ra << 6) + ((((ks << 2) + lg) ^ (ra & 7)) << 3));
        bfr[i] = *(const bf8*)(bC + (rb << 6) + ((((ks << 2) + lg) ^ (rb & 7)) << 3));
      }
      __builtin_amdgcn_s_setprio(1);
      #pragma unroll
      for (int i = 0; i < 4; ++i)
        #pragma unroll
        for (int j = 0; j < 4; ++j)
          acc[i][j] = __builtin_amdgcn_mfma_f32_16x16x32_bf16(af[i], bfr[j], acc[i][j], 0, 0, 0);
      __builtin_amdgcn_s_setprio(0);
    }
    __syncthreads();
  }

  gemm_epilogue44(acc, bias, C, 1024, m0, n0, wm, wn, lr, lg);
}

// ---------------- flash attention: 3-buffer counted-vmcnt pipeline (R9) ------
__global__ __launch_bounds__(256, 3)
void attn_kernel(const u16* __restrict__ Qp, const u16* __restrict__ Kp,
                 const u16* __restrict__ VT, u16* __restrict__ Ob)
{
  __shared__ __align__(16) u16 pool[24576];     // 48 KB: kt[3][4096] | vt[3][4096]
  u16* const ktb = pool;
  u16* const vtb = pool + 12288;

  const int flat = blockIdx.x;
  const int xcd = flat & 7, idx = flat >> 3;
  const int bh = (xcd << 3) + (idx >> 4);
  const int tq0 = (idx & 15) << 7;

  const int tid = threadIdx.x, lane = tid & 63, w = tid >> 6;
  const int ql = lane & 31, hi = lane >> 5;
  const size_t hoff = (size_t)bh * (2048 * 64);
  const u16* Kh = Kp + hoff;
  const u16* Vh = VT + hoff;

  bf8 qf[4];
  {
    const u16* qp_ = Qp + hoff + (size_t)(tq0 + w * 32 + ql) * 64 + hi * 8;
    #pragma unroll
    for (int ks = 0; ks < 4; ++ks) qf[ks] = *(const bf8*)(qp_ + 16 * ks);
  }

  f16v o0 = {}, o1 = {};
  float lrun = 0.f;

  const int c0i = (w << 7) + lane;
  const int c1i = c0i + 64;
  const int sr0 = c0i >> 3, ss0 = ((c0i & 7) ^ (sr0 & 7)) << 3;
  const int sr1 = c1i >> 3, ss1 = ((c1i & 7) ^ (sr1 & 7)) << 3;
  const int sd0 = (w << 10);
  const int sd1 = (w << 10) + 512;

  #define STAGE(buf, t0)                                                          \
    do {                                                                           \
      __builtin_amdgcn_global_load_lds((const AS1 void*)(Kh + (size_t)((t0) + sr0) * 64 + ss0), \
                                       (AS3 void*)(ktb + (buf) * 4096 + sd0), 16, 0, 0);  \
      __builtin_amdgcn_global_load_lds((const AS1 void*)(Kh + (size_t)((t0) + sr1) * 64 + ss1), \
                                       (AS3 void*)(ktb + (buf) * 4096 + sd1), 16, 0, 0);  \
      __builtin_amdgcn_global_load_lds((const AS1 void*)(Vh + (size_t)sr0 * 2048 + (t0) + ss0), \
                                       (AS3 void*)(vtb + (buf) * 4096 + sd0), 16, 0, 0);  \
      __builtin_amdgcn_global_load_lds((const AS1 void*)(Vh + (size_t)sr1 * 2048 + (t0) + ss1), \
                                       (AS3 void*)(vtb + (buf) * 4096 + sd1), 16, 0, 0);  \
    } while (0)

  STAGE(0, 0);
  STAGE(1, 64);

  const int xq = ql & 7;
  int bc = 0;
  for (int it = 0; it < 32; ++it) {
    if (it < 31) asm volatile("s_waitcnt vmcnt(4)" ::: "memory");
    else         asm volatile("s_waitcnt vmcnt(0)" ::: "memory");
    __builtin_amdgcn_s_barrier();
    __builtin_amdgcn_sched_barrier(0);

    if (it + 2 < 32) {
      const int bs = bc ? bc - 1 : 2;
      STAGE(bs, (it + 2) << 6);
    }

    const u16* kb = ktb + bc * 4096;
    const u16* vb = vtb + bc * 4096;

    f16v s0 = {}, s1 = {};
    #pragma unroll
    for (int ks = 0; ks < 4; ++ks) {
      bf8 kf0 = *(const bf8*)(kb + (ql << 6) + ((((ks << 1) + hi) ^ xq) << 3));
      bf8 kf1 = *(const bf8*)(kb + ((32 + ql) << 6) + ((((ks << 1) + hi) ^ xq) << 3));
      __builtin_amdgcn_s_setprio(1);
      s0 = __builtin_amdgcn_mfma_f32_32x32x16_bf16(kf0, qf[ks], s0, 0, 0, 0);
      s1 = __builtin_amdgcn_mfma_f32_32x32x16_bf16(kf1, qf[ks], s1, 0, 0, 0);
      __builtin_amdgcn_s_setprio(0);
    }

    bf8 vf0[4], vf1[4];
    #pragma unroll
    for (int ks = 0; ks < 4; ++ks) {
      vf0[ks] = *(const bf8*)(vb + (ql << 6) + ((((ks << 1) + hi) ^ xq) << 3));
      vf1[ks] = *(const bf8*)(vb + ((32 + ql) << 6) + ((((ks << 1) + hi) ^ xq) << 3));
    }

    float rs = 0.f;

    {
      unsigned wpk[8];
      #pragma unroll
      for (int i = 0; i < 8; ++i) {
        float e0 = __builtin_amdgcn_exp2f(s0[2 * i]);
        float e1 = __builtin_amdgcn_exp2f(s0[2 * i + 1]);
        rs += e0 + e1;
        wpk[i] = cvtpk(e0, e1);
      }
      swap32(wpk[0], wpk[2]); swap32(wpk[1], wpk[3]);
      swap32(wpk[4], wpk[6]); swap32(wpk[5], wpk[7]);
      bf8 pf0 = __builtin_bit_cast(bf8, make_uint4(wpk[0], wpk[1], wpk[2], wpk[3]));
      bf8 pf1 = __builtin_bit_cast(bf8, make_uint4(wpk[4], wpk[5], wpk[6], wpk[7]));
      __builtin_amdgcn_s_setprio(1);
      o0 = __builtin_amdgcn_mfma_f32_32x32x16_bf16(vf0[0], pf0, o0, 0, 0, 0);
      o1 = __builtin_amdgcn_mfma_f32_32x32x16_bf16(vf1[0], pf0, o1, 0, 0, 0);
      o0 = __builtin_amdgcn_mfma_f32_32x32x16_bf16(vf0[1], pf1, o0, 0, 0, 0);
      o1 = __builtin_amdgcn_mfma_f32_32x32x16_bf16(vf1[1], pf1, o1, 0, 0, 0);
      __builtin_amdgcn_s_setprio(0);
    }

    {
      unsigned wpk[8];
      #pragma unroll
      for (int i = 0; i < 8; ++i) {
        float e0 = __builtin_amdgcn_exp2f(s1[2 * i]);
        float e1 = __builtin_amdgcn_exp2f(s1[2 * i + 1]);
        rs += e0 + e1;
        wpk[i] = cvtpk(e0, e1);
      }
      swap32(wpk[0], wpk[2]); swap32(wpk[1], wpk[3]);
      swap32(wpk[4], wpk[6]); swap32(wpk[5], wpk[7]);
      bf8 pf2 = __builtin_bit_cast(bf8, make_uint4(wpk[0], wpk[1], wpk[2], wpk[3]));
      bf8 pf3 = __builtin_bit_cast(bf8, make_uint4(wpk[4], wpk[5], wpk[6], wpk[7]));
      __builtin_amdgcn_s_setprio(1);
      o0 = __builtin_amdgcn_mfma_f32_32x32x16_bf16(vf0[2], pf2, o0, 0, 0, 0);
      o1 = __builtin_amdgcn_mfma_f32_32x32x16_bf16(vf1[2], pf2, o1, 0, 0, 0);
      o0 = __builtin_amdgcn_mfma_f32_32x32x16_bf16(vf0[3], pf3, o0, 0, 0, 0);
      o1 = __builtin_amdgcn_mfma_f32_32x32x16_bf16(vf1[3], pf3, o1, 0, 0, 0);
      __builtin_amdgcn_s_setprio(0);
    }

    lrun += rs;
    bc = bc + 1 < 3 ? bc + 1 : 0;
  }
  #undef STAGE

  const float linv = 1.f / (lrun + __shfl_xor(lrun, 32));

  __syncthreads();
  u16* const ot = pool;
  const int orow = w * 32 + ql;
  #pragma unroll
  for (int c = 0; c < 2; ++c) {
    const f16v& o = c ? o1 : o0;
    #pragma unroll
    for (int g = 0; g < 4; ++g) {
      uint2 pk;
      pk.x = cvtpk(o[4 * g + 0] * linv, o[4 * g + 1] * linv);
      pk.y = cvtpk(o[4 * g + 2] * linv, o[4 * g + 3] * linv);
      *(uint2*)(ot + orow * 72 + 32 * c + 8 * g + 4 * hi) = pk;
    }
  }
  __syncthreads();

  const int b = bh >> 4, h = bh & 15;
  const int row = tid >> 1, seg = tid & 1;
  const u16* src = ot + row * 72 + seg * 32;
  u16* dst = Ob + ((size_t)(b * 2048 + tq0 + row) * 16 + h) * 64 + seg * 32;
  #pragma unroll
  for (int kk = 0; kk < 4; ++kk)
    *(uint4*)(dst + 8 * kk) = *(const uint4*)(src + 8 * kk);
}

// ---------------- host launch ----------------
extern "C" void kernel_launch(void* const* d_in, const int* in_sizes, int n_in,
                              void* d_out, int out_size, void* d_ws, size_t ws_size,
                              hipStream_t stream) {
  (void)in_sizes; (void)n_in; (void)out_size; (void)ws_size;
  const float* k_in = (const float*)d_in[0];
  const float* q_in = (const float*)d_in[1];
  const float* v_in = (const float*)d_in[2];
  const float* Wk = (const float*)d_in[3]; const float* bk = (const float*)d_in[4];
  const float* Wq = (const float*)d_in[5]; const float* bq = (const float*)d_in[6];
  const float* Wv = (const float*)d_in[7]; const float* bv = (const float*)d_in[8];
  const float* Wo = (const float*)d_in[9]; const float* bo = (const float*)d_in[10];
  float* out = (float*)d_out;

  char* ws = (char*)d_ws;
  const size_t SZ_ACT = (size_t)8192 * 1024 * 2;   // 16 MB bf16
  const size_t SZ_W   = (size_t)1024 * 1024 * 2;   // 2 MB bf16
  u16* Oc  = (u16*)(ws);
  u16* Qp  = (u16*)(ws + 1 * SZ_ACT);
  u16* Kp  = (u16*)(ws + 2 * SZ_ACT);
  u16* Vt  = (u16*)(ws + 3 * SZ_ACT);               // [B,H,CH,T]
  u16* Wqb = (u16*)(ws + 4 * SZ_ACT);
  u16* Wkb = (u16*)(ws + 4 * SZ_ACT + SZ_W);
  u16* Wvb = (u16*)(ws + 4 * SZ_ACT + 2 * SZ_W);
  u16* Wob = (u16*)(ws + 4 * SZ_ACT + 3 * SZ_W);

  // weights: one fused convert (outputs contiguous Wq|Wk|Wv|Wo)
  cvt4_kernel<<<4096, 256, 0, stream>>>(Wq, Wk, Wv, Wo, Wqb);

  const float c0 = 0.125f * 1.4426950408889634f;    // softmax scale * log2(e)

  // merged projections: Q (pre-scaled), K -> [B,H,T,CH]; V -> [B,H,CH,T]
  proj_qkv<<<1536, 512, 0, stream>>>(q_in, k_in, v_in, Wqb, Wkb, Wvb,
                                     bq, bk, bv, Qp, Kp, Vt, c0);

  // flash attention -> [B,T,C] bf16
  attn_kernel<<<1024, 256, 0, stream>>>(Qp, Kp, Vt, Oc);

  // output projection -> fp32
  gemm_out<<<512, 256, 0, stream>>>(Oc, Wob, bo, out);
}